// Round 1
// baseline (456.885 us; speedup 1.0000x reference)
//
#include <hip/hip_runtime.h>
#include <math.h>

#define E_TYPES 20
#define NBLK 2
#define NANG 7
#define CS 384
#define CH 128
#define N_TOK (8 * 2048)
#define TOK 32          // tokens per block in main kernel
#define TPB 256         // threads per block in main kernel
#define KC 128          // k-chunk for the c_s=384 input matvec
#define MAX_TILES (N_TOK / TOK + E_TYPES)   // 512 + 20 = 532

// ---- workspace layout (ints) ----
#define CNT_OFF 0            // 20 counts
#define OFFS_OFF 32          // 21 offsets
#define CUR_OFF 64           // 20 cursors
#define NT_OFF 96            // 1 num_tiles
#define TT_OFF 128           // MAX_TILES tile_type
#define TS_OFF (TT_OFF + MAX_TILES)    // tile_start (position in perm)
#define TN_OFF (TS_OFF + MAX_TILES)    // tile token count
#define PERM_OFF 2048        // N_TOK perm entries
// total ints: 2048 + 16384 = 18432 -> 73,728 bytes of d_ws

__global__ void init_k(int* ws) {
    int t = threadIdx.x;
    if (t < 128) ws[t] = 0;   // zero counts/offsets/cursors/num_tiles region
}

__global__ void count_k(const int* __restrict__ aatype, int* ws) {
    int idx = blockIdx.x * blockDim.x + threadIdx.x;
    if (idx < N_TOK) atomicAdd(&ws[CNT_OFF + aatype[idx]], 1);
}

__global__ void plan_k(int* ws) {
    if (threadIdx.x != 0) return;
    int off = 0;
    for (int e = 0; e < E_TYPES; e++) {
        ws[OFFS_OFF + e] = off;
        off += ws[CNT_OFF + e];
    }
    ws[OFFS_OFF + E_TYPES] = off;
    int nt = 0;
    for (int e = 0; e < E_TYPES; e++) {
        int cnt = ws[CNT_OFF + e];
        int base = ws[OFFS_OFF + e];
        for (int st = 0; st < cnt; st += TOK) {
            ws[TT_OFF + nt] = e;
            ws[TS_OFF + nt] = base + st;
            ws[TN_OFF + nt] = (cnt - st < TOK) ? (cnt - st) : TOK;
            nt++;
        }
    }
    ws[NT_OFF] = nt;
}

__global__ void scatter_k(const int* __restrict__ aatype, int* ws) {
    int idx = blockIdx.x * blockDim.x + threadIdx.x;
    if (idx < N_TOK) {
        int e = aatype[idx];
        int pos = ws[OFFS_OFF + e] + atomicAdd(&ws[CUR_OFF + e], 1);
        ws[PERM_OFF + pos] = idx;
    }
}

__global__ __launch_bounds__(TPB, 2)
void angle_main(const float* __restrict__ s, const float* __restrict__ si,
                const float* __restrict__ Win, const float* __restrict__ b_in,
                const float* __restrict__ Winit, const float* __restrict__ b_init2,
                const float* __restrict__ Wb1, const float* __restrict__ bb1,
                const float* __restrict__ Wb2, const float* __restrict__ bb2,
                const float* __restrict__ Wout, const float* __restrict__ b_out,
                const int* __restrict__ ws, float* __restrict__ out)
{
    __shared__ float sfb[TOK][KC];       // relu(s) chunk
    __shared__ float sib[TOK][KC];       // relu(s_init) chunk
    __shared__ float hb[TOK][CH + 1];    // stride 129: (i*129+k)%32 spreads banks
    __shared__ float ab[TOK][CH + 1];
    __shared__ int ptok[TOK];

    int nt = ws[NT_OFF];
    int bid = blockIdx.x;
    if (bid >= nt) return;
    int e     = ws[TT_OFF + bid];
    int start = ws[TS_OFF + bid];
    int n     = ws[TN_OFF + bid];

    int t = threadIdx.x;
    if (t < TOK) ptok[t] = ws[PERM_OFF + start + ((t < n) ? t : 0)];
    __syncthreads();

    int j = t & (CH - 1);
    int half = t >> 7;              // 0 or 1; each half handles 16 tokens
    int ibase = half * (TOK / 2);

    float acc[TOK / 2];             // h[i][j] for my 16 tokens, channel j
    {
        float binit = b_in[e * CH + j] + b_init2[e * CH + j];
        #pragma unroll
        for (int ii = 0; ii < TOK / 2; ii++) acc[ii] = binit;
    }

    const float* WinE   = Win   + (size_t)e * CS * CH;
    const float* WinitE = Winit + (size_t)e * CS * CH;

    // ---- h = relu(s) @ Win + relu(s_init) @ Winit + biases, chunked over c_s ----
    for (int kc = 0; kc < CS; kc += KC) {
        __syncthreads();
        for (int idx = t; idx < TOK * (KC / 4); idx += TPB) {
            int i = idx >> 5;          // KC/4 == 32
            int c4 = idx & 31;
            float4 v = make_float4(0.f, 0.f, 0.f, 0.f);
            float4 w = make_float4(0.f, 0.f, 0.f, 0.f);
            if (i < n) {
                const float4* ps = (const float4*)(s  + (size_t)ptok[i] * CS + kc);
                const float4* pi = (const float4*)(si + (size_t)ptok[i] * CS + kc);
                v = ps[c4];
                w = pi[c4];
            }
            v.x = fmaxf(v.x, 0.f); v.y = fmaxf(v.y, 0.f);
            v.z = fmaxf(v.z, 0.f); v.w = fmaxf(v.w, 0.f);
            w.x = fmaxf(w.x, 0.f); w.y = fmaxf(w.y, 0.f);
            w.z = fmaxf(w.z, 0.f); w.w = fmaxf(w.w, 0.f);
            ((float4*)&sfb[i][0])[c4] = v;
            ((float4*)&sib[i][0])[c4] = w;
        }
        __syncthreads();
        const float* w1p = WinE   + (size_t)kc * CH + j;
        const float* w2p = WinitE + (size_t)kc * CH + j;
        #pragma unroll 4
        for (int d = 0; d < KC; d++) {
            float w1 = w1p[(size_t)d * CH];
            float w2 = w2p[(size_t)d * CH];
            #pragma unroll
            for (int ii = 0; ii < TOK / 2; ii++) {
                acc[ii] = fmaf(sfb[ibase + ii][d], w1, acc[ii]);
                acc[ii] = fmaf(sib[ibase + ii][d], w2, acc[ii]);
            }
        }
    }

    // ---- 2 residual blocks: h += Wb2 @ relu(Wb1 @ relu(h) + bb1) + bb2 ----
    for (int b = 0; b < NBLK; b++) {
        __syncthreads();
        #pragma unroll
        for (int ii = 0; ii < TOK / 2; ii++) hb[ibase + ii][j] = fmaxf(acc[ii], 0.f);
        __syncthreads();

        float aacc[TOK / 2];
        {
            float bb = bb1[(e * NBLK + b) * CH + j];
            #pragma unroll
            for (int ii = 0; ii < TOK / 2; ii++) aacc[ii] = bb;
        }
        const float* W1p = Wb1 + ((size_t)(e * NBLK + b) * CH) * CH + j;
        #pragma unroll 4
        for (int k = 0; k < CH; k++) {
            float w = W1p[(size_t)k * CH];
            #pragma unroll
            for (int ii = 0; ii < TOK / 2; ii++)
                aacc[ii] = fmaf(hb[ibase + ii][k], w, aacc[ii]);
        }
        __syncthreads();
        #pragma unroll
        for (int ii = 0; ii < TOK / 2; ii++) ab[ibase + ii][j] = fmaxf(aacc[ii], 0.f);
        __syncthreads();

        {
            float bb = bb2[(e * NBLK + b) * CH + j];
            #pragma unroll
            for (int ii = 0; ii < TOK / 2; ii++) aacc[ii] = bb;
        }
        const float* W2p = Wb2 + ((size_t)(e * NBLK + b) * CH) * CH + j;
        #pragma unroll 4
        for (int k = 0; k < CH; k++) {
            float w = W2p[(size_t)k * CH];
            #pragma unroll
            for (int ii = 0; ii < TOK / 2; ii++)
                aacc[ii] = fmaf(ab[ibase + ii][k], w, aacc[ii]);
        }
        #pragma unroll
        for (int ii = 0; ii < TOK / 2; ii++) acc[ii] += aacc[ii];
    }

    // ---- final relu(h) to LDS ----
    __syncthreads();
    #pragma unroll
    for (int ii = 0; ii < TOK / 2; ii++) hb[ibase + ii][j] = fmaxf(acc[ii], 0.f);
    __syncthreads();

    // ---- out = relu(h) @ Wout + b_out  (128 -> 14), then pair-normalize ----
    const float* WoutE = Wout + (size_t)e * CH * (NANG * 2);
    const float* boutE = b_out + e * (NANG * 2);
    for (int idx = t; idx < n * (NANG * 2); idx += TPB) {
        int i = idx / (NANG * 2);
        int o = idx % (NANG * 2);
        float v = boutE[o];
        #pragma unroll 4
        for (int k = 0; k < CH; k++)
            v = fmaf(hb[i][k], WoutE[(size_t)k * (NANG * 2) + o], v);
        ab[i][o] = v;
    }
    __syncthreads();
    for (int idx = t; idx < n * NANG; idx += TPB) {
        int i = idx / NANG;
        int a = idx % NANG;
        float x = ab[i][2 * a];
        float y = ab[i][2 * a + 1];
        float nr = fmaxf(sqrtf(x * x + y * y), 1e-12f);
        size_t base = (size_t)ptok[i] * (NANG * 2) + 2 * a;
        out[base]     = x / nr;
        out[base + 1] = y / nr;
    }
}

extern "C" void kernel_launch(void* const* d_in, const int* in_sizes, int n_in,
                              void* d_out, int out_size, void* d_ws, size_t ws_size,
                              hipStream_t stream) {
    const float* s       = (const float*)d_in[0];
    const float* s_init  = (const float*)d_in[1];
    const int*   aatype  = (const int*)d_in[2];
    const float* Win     = (const float*)d_in[3];
    const float* b_in    = (const float*)d_in[4];
    const float* Winit   = (const float*)d_in[5];
    const float* b_init2 = (const float*)d_in[6];
    const float* Wb1     = (const float*)d_in[7];
    const float* bb1     = (const float*)d_in[8];
    const float* Wb2     = (const float*)d_in[9];
    const float* bb2     = (const float*)d_in[10];
    const float* Wout    = (const float*)d_in[11];
    const float* b_out   = (const float*)d_in[12];
    int*   ws  = (int*)d_ws;
    float* out = (float*)d_out;

    hipLaunchKernelGGL(init_k, dim3(1), dim3(128), 0, stream, ws);
    hipLaunchKernelGGL(count_k, dim3((N_TOK + 255) / 256), dim3(256), 0, stream, aatype, ws);
    hipLaunchKernelGGL(plan_k, dim3(1), dim3(64), 0, stream, ws);
    hipLaunchKernelGGL(scatter_k, dim3((N_TOK + 255) / 256), dim3(256), 0, stream, aatype, ws);
    hipLaunchKernelGGL(angle_main, dim3(MAX_TILES), dim3(TPB), 0, stream,
                       s, s_init, Win, b_in, Winit, b_init2,
                       Wb1, bb1, Wb2, bb2, Wout, b_out, ws, out);
}

// Round 2
// 262.263 us; speedup vs baseline: 1.7421x; 1.7421x over previous
//
#include <hip/hip_runtime.h>
#include <math.h>

#define E_TYPES 20
#define NBLK 2
#define NANG 7
#define CS 384
#define CH 128
#define N_TOK (8 * 2048)
#define TOK 32          // tokens per block in main kernel
#define TPB 256         // threads per block in main kernel
#define KC 128          // k-chunk for the c_s=384 input matvec
#define MAX_TILES (N_TOK / TOK + E_TYPES)   // 512 + 20 = 532
#define SROW 132        // padded LDS row stride (floats), 16B-aligned rows

// ---- workspace layout (ints) ----
#define CNT_OFF 0            // 20 counts
#define OFFS_OFF 32          // 21 offsets
#define CUR_OFF 64           // 20 cursors
#define NT_OFF 96            // 1 num_tiles
#define TT_OFF 128           // MAX_TILES tile_type
#define TS_OFF (TT_OFF + MAX_TILES)    // tile_start (position in perm)
#define TN_OFF (TS_OFF + MAX_TILES)    // tile token count
#define PERM_OFF 2048        // N_TOK perm entries

__global__ void init_k(int* ws) {
    int t = threadIdx.x;
    if (t < 128) ws[t] = 0;
}

// LDS-aggregated histogram: 20 global atomics per block instead of 256.
__global__ void count_k(const int* __restrict__ aatype, int* ws) {
    __shared__ int lh[E_TYPES];
    int t = threadIdx.x;
    if (t < E_TYPES) lh[t] = 0;
    __syncthreads();
    int idx = blockIdx.x * blockDim.x + t;
    if (idx < N_TOK) atomicAdd(&lh[aatype[idx]], 1);
    __syncthreads();
    if (t < E_TYPES && lh[t] > 0) atomicAdd(&ws[CNT_OFF + t], lh[t]);
}

__global__ void plan_k(int* ws) {
    if (threadIdx.x != 0) return;
    int off = 0;
    for (int e = 0; e < E_TYPES; e++) {
        ws[OFFS_OFF + e] = off;
        off += ws[CNT_OFF + e];
    }
    ws[OFFS_OFF + E_TYPES] = off;
    int nt = 0;
    for (int e = 0; e < E_TYPES; e++) {
        int cnt = ws[CNT_OFF + e];
        int base = ws[OFFS_OFF + e];
        for (int st = 0; st < cnt; st += TOK) {
            ws[TT_OFF + nt] = e;
            ws[TS_OFF + nt] = base + st;
            ws[TN_OFF + nt] = (cnt - st < TOK) ? (cnt - st) : TOK;
            nt++;
        }
    }
    ws[NT_OFF] = nt;
}

// Block-aggregated scatter: reserve per-bin ranges once per block, rank
// within block via LDS atomics. Order within a type is arbitrary — every
// token writes its own output slot, so any permutation is correct.
__global__ void scatter_k(const int* __restrict__ aatype, int* ws) {
    __shared__ int lh[E_TYPES], lbase[E_TYPES], lcur[E_TYPES];
    int t = threadIdx.x;
    if (t < E_TYPES) { lh[t] = 0; lcur[t] = 0; }
    __syncthreads();
    int idx = blockIdx.x * blockDim.x + t;
    int e = -1;
    if (idx < N_TOK) {
        e = aatype[idx];
        atomicAdd(&lh[e], 1);
    }
    __syncthreads();
    if (t < E_TYPES && lh[t] > 0)
        lbase[t] = ws[OFFS_OFF + t] + atomicAdd(&ws[CUR_OFF + t], lh[t]);
    __syncthreads();
    if (idx < N_TOK) {
        int r = atomicAdd(&lcur[e], 1);
        ws[PERM_OFF + lbase[e] + r] = idx;
    }
}

#define LD4(dst, ptr) { float4 _v = *(const float4*)(ptr); \
    (dst)[0] = _v.x; (dst)[1] = _v.y; (dst)[2] = _v.z; (dst)[3] = _v.w; }

__global__ __launch_bounds__(TPB, 4)
void angle_main(const float* __restrict__ s, const float* __restrict__ si,
                const float* __restrict__ Win, const float* __restrict__ b_in,
                const float* __restrict__ Winit, const float* __restrict__ b_init2,
                const float* __restrict__ Wb1, const float* __restrict__ bb1,
                const float* __restrict__ Wb2, const float* __restrict__ bb2,
                const float* __restrict__ Wout, const float* __restrict__ b_out,
                const int* __restrict__ ws, float* __restrict__ out)
{
    // Aliased LDS: phase 1 uses smem[0]=relu(s) chunk, smem[1]=relu(si) chunk;
    // phase 2 uses smem[0]=h, smem[1]=a. 2*32*132*4 = 33792 B -> 4 blocks/CU.
    __shared__ float smem[2][TOK][SROW];
    __shared__ int ptok[TOK];

    int nt = ws[NT_OFF];
    int bid = blockIdx.x;
    if (bid >= nt) return;
    int e     = ws[TT_OFF + bid];
    int start = ws[TS_OFF + bid];
    int n     = ws[TN_OFF + bid];

    int t = threadIdx.x;
    if (t < TOK) ptok[t] = ws[PERM_OFF + start + ((t < n) ? t : 0)];
    __syncthreads();

    // Register tile: 4 tokens x 4 channels per thread.
    int cgrp = t & 31;          // channels 4*cgrp .. 4*cgrp+3
    int tgrp = t >> 5;          // tokens  4*tgrp .. 4*tgrp+3
    int c0 = 4 * cgrp;
    int tok0 = 4 * tgrp;

    float acc[4][4];            // [token][channel] = h
    {
        float bi[4], b2[4];
        LD4(bi, b_in    + (size_t)e * CH + c0);
        LD4(b2, b_init2 + (size_t)e * CH + c0);
        #pragma unroll
        for (int tt = 0; tt < 4; tt++)
            #pragma unroll
            for (int cc = 0; cc < 4; cc++)
                acc[tt][cc] = bi[cc] + b2[cc];
    }

    const float* WinE   = Win   + (size_t)e * CS * CH;
    const float* WinitE = Winit + (size_t)e * CS * CH;

    // ---- h = relu(s) @ Win + relu(s_init) @ Winit + biases ----
    for (int kc = 0; kc < CS; kc += KC) {
        __syncthreads();
        for (int idx = t; idx < TOK * (KC / 4); idx += TPB) {
            int i = idx >> 5;          // KC/4 == 32
            int c4 = idx & 31;
            float4 v = make_float4(0.f, 0.f, 0.f, 0.f);
            float4 w = make_float4(0.f, 0.f, 0.f, 0.f);
            if (i < n) {
                v = *(const float4*)(s  + (size_t)ptok[i] * CS + kc + 4 * c4);
                w = *(const float4*)(si + (size_t)ptok[i] * CS + kc + 4 * c4);
            }
            v.x = fmaxf(v.x, 0.f); v.y = fmaxf(v.y, 0.f);
            v.z = fmaxf(v.z, 0.f); v.w = fmaxf(v.w, 0.f);
            w.x = fmaxf(w.x, 0.f); w.y = fmaxf(w.y, 0.f);
            w.z = fmaxf(w.z, 0.f); w.w = fmaxf(w.w, 0.f);
            *(float4*)&smem[0][i][4 * c4] = v;
            *(float4*)&smem[1][i][4 * c4] = w;
        }
        __syncthreads();
        #pragma unroll 2
        for (int k4 = 0; k4 < KC; k4 += 4) {
            float aA[4][4], aB[4][4];      // [token][kk]
            #pragma unroll
            for (int tt = 0; tt < 4; tt++) {
                LD4(aA[tt], &smem[0][tok0 + tt][k4]);
                LD4(aB[tt], &smem[1][tok0 + tt][k4]);
            }
            #pragma unroll
            for (int kk = 0; kk < 4; kk++) {
                float wA[4], wB[4];
                LD4(wA, WinE   + (size_t)(kc + k4 + kk) * CH + c0);
                LD4(wB, WinitE + (size_t)(kc + k4 + kk) * CH + c0);
                #pragma unroll
                for (int tt = 0; tt < 4; tt++)
                    #pragma unroll
                    for (int cc = 0; cc < 4; cc++)
                        acc[tt][cc] = fmaf(aA[tt][kk], wA[cc],
                                      fmaf(aB[tt][kk], wB[cc], acc[tt][cc]));
            }
        }
    }

    // ---- 2 residual blocks ----
    for (int b = 0; b < NBLK; b++) {
        __syncthreads();   // prior readers of smem done
        #pragma unroll
        for (int tt = 0; tt < 4; tt++) {
            float4 v = make_float4(fmaxf(acc[tt][0], 0.f), fmaxf(acc[tt][1], 0.f),
                                   fmaxf(acc[tt][2], 0.f), fmaxf(acc[tt][3], 0.f));
            *(float4*)&smem[0][tok0 + tt][c0] = v;
        }
        __syncthreads();

        float a2[4][4];
        {
            float bb[4];
            LD4(bb, bb1 + (size_t)(e * NBLK + b) * CH + c0);
            #pragma unroll
            for (int tt = 0; tt < 4; tt++)
                #pragma unroll
                for (int cc = 0; cc < 4; cc++) a2[tt][cc] = bb[cc];
        }
        const float* W1 = Wb1 + (size_t)(e * NBLK + b) * CH * CH;
        #pragma unroll 2
        for (int k4 = 0; k4 < CH; k4 += 4) {
            float hv[4][4];
            #pragma unroll
            for (int tt = 0; tt < 4; tt++) LD4(hv[tt], &smem[0][tok0 + tt][k4]);
            #pragma unroll
            for (int kk = 0; kk < 4; kk++) {
                float w1[4];
                LD4(w1, W1 + (size_t)(k4 + kk) * CH + c0);
                #pragma unroll
                for (int tt = 0; tt < 4; tt++)
                    #pragma unroll
                    for (int cc = 0; cc < 4; cc++)
                        a2[tt][cc] = fmaf(hv[tt][kk], w1[cc], a2[tt][cc]);
            }
        }
        __syncthreads();
        #pragma unroll
        for (int tt = 0; tt < 4; tt++) {
            float4 v = make_float4(fmaxf(a2[tt][0], 0.f), fmaxf(a2[tt][1], 0.f),
                                   fmaxf(a2[tt][2], 0.f), fmaxf(a2[tt][3], 0.f));
            *(float4*)&smem[1][tok0 + tt][c0] = v;
        }
        __syncthreads();

        {
            float bb[4];
            LD4(bb, bb2 + (size_t)(e * NBLK + b) * CH + c0);
            #pragma unroll
            for (int tt = 0; tt < 4; tt++)
                #pragma unroll
                for (int cc = 0; cc < 4; cc++) a2[tt][cc] = bb[cc];
        }
        const float* W2 = Wb2 + (size_t)(e * NBLK + b) * CH * CH;
        #pragma unroll 2
        for (int k4 = 0; k4 < CH; k4 += 4) {
            float av[4][4];
            #pragma unroll
            for (int tt = 0; tt < 4; tt++) LD4(av[tt], &smem[1][tok0 + tt][k4]);
            #pragma unroll
            for (int kk = 0; kk < 4; kk++) {
                float w2[4];
                LD4(w2, W2 + (size_t)(k4 + kk) * CH + c0);
                #pragma unroll
                for (int tt = 0; tt < 4; tt++)
                    #pragma unroll
                    for (int cc = 0; cc < 4; cc++)
                        a2[tt][cc] = fmaf(av[tt][kk], w2[cc], a2[tt][cc]);
            }
        }
        #pragma unroll
        for (int tt = 0; tt < 4; tt++)
            #pragma unroll
            for (int cc = 0; cc < 4; cc++) acc[tt][cc] += a2[tt][cc];
    }

    // ---- final relu(h) -> LDS ----
    __syncthreads();
    #pragma unroll
    for (int tt = 0; tt < 4; tt++) {
        float4 v = make_float4(fmaxf(acc[tt][0], 0.f), fmaxf(acc[tt][1], 0.f),
                               fmaxf(acc[tt][2], 0.f), fmaxf(acc[tt][3], 0.f));
        *(float4*)&smem[0][tok0 + tt][c0] = v;
    }
    __syncthreads();

    // ---- out = relu(h) @ Wout + b_out (128 -> 14) ----
    const float* WoutE = Wout + (size_t)e * CH * (NANG * 2);
    const float* boutE = b_out + (size_t)e * (NANG * 2);
    for (int idx = t; idx < n * (NANG * 2); idx += TPB) {
        int i = idx / (NANG * 2);
        int o = idx % (NANG * 2);
        float v = boutE[o];
        #pragma unroll 4
        for (int k = 0; k < CH; k++)
            v = fmaf(smem[0][i][k], WoutE[(size_t)k * (NANG * 2) + o], v);
        smem[1][i][o] = v;
    }
    __syncthreads();

    // ---- pair-normalize and store ----
    for (int idx = t; idx < n * NANG; idx += TPB) {
        int i = idx / NANG;
        int a = idx % NANG;
        float x = smem[1][i][2 * a];
        float y = smem[1][i][2 * a + 1];
        float nr = fmaxf(sqrtf(x * x + y * y), 1e-12f);
        size_t base = (size_t)ptok[i] * (NANG * 2) + 2 * a;
        out[base]     = x / nr;
        out[base + 1] = y / nr;
    }
}

extern "C" void kernel_launch(void* const* d_in, const int* in_sizes, int n_in,
                              void* d_out, int out_size, void* d_ws, size_t ws_size,
                              hipStream_t stream) {
    const float* s       = (const float*)d_in[0];
    const float* s_init  = (const float*)d_in[1];
    const int*   aatype  = (const int*)d_in[2];
    const float* Win     = (const float*)d_in[3];
    const float* b_in    = (const float*)d_in[4];
    const float* Winit   = (const float*)d_in[5];
    const float* b_init2 = (const float*)d_in[6];
    const float* Wb1     = (const float*)d_in[7];
    const float* bb1     = (const float*)d_in[8];
    const float* Wb2     = (const float*)d_in[9];
    const float* bb2     = (const float*)d_in[10];
    const float* Wout    = (const float*)d_in[11];
    const float* b_out   = (const float*)d_in[12];
    int*   ws  = (int*)d_ws;
    float* out = (float*)d_out;

    hipLaunchKernelGGL(init_k, dim3(1), dim3(128), 0, stream, ws);
    hipLaunchKernelGGL(count_k, dim3(N_TOK / 256), dim3(256), 0, stream, aatype, ws);
    hipLaunchKernelGGL(plan_k, dim3(1), dim3(64), 0, stream, ws);
    hipLaunchKernelGGL(scatter_k, dim3(N_TOK / 256), dim3(256), 0, stream, aatype, ws);
    hipLaunchKernelGGL(angle_main, dim3(MAX_TILES), dim3(TPB), 0, stream,
                       s, s_init, Win, b_in, Winit, b_init2,
                       Wb1, bb1, Wb2, bb2, Wout, b_out, ws, out);
}

// Round 3
// 243.881 us; speedup vs baseline: 1.8734x; 1.0754x over previous
//
#include <hip/hip_runtime.h>
#include <math.h>

#define E_TYPES 20
#define NBLK 2
#define NANG 7
#define CS 384
#define CH 128
#define N_TOK (8 * 2048)
#define TOK 32          // tokens per tile
#define TPB 256         // threads per block, 4 waves
#define KC 128          // k-chunk for the c_s=384 input staging
#define MAX_TILES (N_TOK / TOK + E_TYPES)   // 532
#define SROW 132        // padded LDS row stride (floats)

// ---- workspace layout (ints) ----
#define CNT_OFF 0            // 20 counts
#define CUR_OFF 32           // 20 cursors
#define POFF_OFF 64          // 21 padded offsets (multiples of 32)
#define PERM_OFF 2048        // padded perm entries

__global__ void count_k(const int* __restrict__ aatype, int* ws) {
    __shared__ int lh[E_TYPES];
    int t = threadIdx.x;
    if (t < E_TYPES) lh[t] = 0;
    __syncthreads();
    int idx = blockIdx.x * blockDim.x + t;
    if (idx < N_TOK) atomicAdd(&lh[aatype[idx]], 1);
    __syncthreads();
    if (t < E_TYPES && lh[t] > 0) atomicAdd(&ws[CNT_OFF + t], lh[t]);
}

// padded prefix: poff[e+1] = poff[e] + roundup32(cnt[e]); only 21 writes.
__global__ void offs_k(int* ws) {
    if (threadIdx.x != 0) return;
    int off = 0;
    #pragma unroll
    for (int e = 0; e < E_TYPES; e++) {
        ws[POFF_OFF + e] = off;
        off += (ws[CNT_OFF + e] + TOK - 1) & ~(TOK - 1);
    }
    ws[POFF_OFF + E_TYPES] = off;
}

// Block-aggregated scatter into padded layout.
__global__ void scatter_k(const int* __restrict__ aatype, int* ws) {
    __shared__ int lh[E_TYPES], lbase[E_TYPES], lcur[E_TYPES];
    int t = threadIdx.x;
    if (t < E_TYPES) { lh[t] = 0; lcur[t] = 0; }
    __syncthreads();
    int idx = blockIdx.x * blockDim.x + t;
    int e = -1;
    if (idx < N_TOK) {
        e = aatype[idx];
        atomicAdd(&lh[e], 1);
    }
    __syncthreads();
    if (t < E_TYPES && lh[t] > 0)
        lbase[t] = ws[POFF_OFF + t] + atomicAdd(&ws[CUR_OFF + t], lh[t]);
    __syncthreads();
    if (idx < N_TOK) {
        int r = atomicAdd(&lcur[e], 1);
        ws[PERM_OFF + lbase[e] + r] = idx;
    }
}

#define LD4(dst, ptr) { float4 _v = *(const float4*)(ptr); \
    (dst)[0] = _v.x; (dst)[1] = _v.y; (dst)[2] = _v.z; (dst)[3] = _v.w; }

#define PRELOAD2(wa, wb, pA, pB, krow) { \
    wa[0] = *(const float4*)((pA) + (size_t)((krow) + 0) * CH + c0); \
    wa[1] = *(const float4*)((pA) + (size_t)((krow) + 1) * CH + c0); \
    wa[2] = *(const float4*)((pA) + (size_t)((krow) + 2) * CH + c0); \
    wa[3] = *(const float4*)((pA) + (size_t)((krow) + 3) * CH + c0); \
    wb[0] = *(const float4*)((pB) + (size_t)((krow) + 0) * CH + c0); \
    wb[1] = *(const float4*)((pB) + (size_t)((krow) + 1) * CH + c0); \
    wb[2] = *(const float4*)((pB) + (size_t)((krow) + 2) * CH + c0); \
    wb[3] = *(const float4*)((pB) + (size_t)((krow) + 3) * CH + c0); }

#define PRELOAD1(wa, pA, krow) { \
    wa[0] = *(const float4*)((pA) + (size_t)((krow) + 0) * CH + c0); \
    wa[1] = *(const float4*)((pA) + (size_t)((krow) + 1) * CH + c0); \
    wa[2] = *(const float4*)((pA) + (size_t)((krow) + 2) * CH + c0); \
    wa[3] = *(const float4*)((pA) + (size_t)((krow) + 3) * CH + c0); }

#define WF(buf, kk, cc) (((const float*)&(buf)[kk])[cc])

__global__ __launch_bounds__(TPB, 2)
void angle_main(const float* __restrict__ s, const float* __restrict__ si,
                const float* __restrict__ Win, const float* __restrict__ b_in,
                const float* __restrict__ Winit, const float* __restrict__ b_init2,
                const float* __restrict__ Wb1, const float* __restrict__ bb1,
                const float* __restrict__ Wb2, const float* __restrict__ bb2,
                const float* __restrict__ Wout, const float* __restrict__ b_out,
                const int* __restrict__ ws, float* __restrict__ out)
{
    __shared__ float smem[2][TOK][SROW];
    __shared__ int ptok[TOK];

    int pos = blockIdx.x * TOK;
    if (pos >= ws[POFF_OFF + E_TYPES]) return;
    int e = 0;
    while (e < E_TYPES - 1 && pos >= ws[POFF_OFF + e + 1]) e++;
    int n = ws[CNT_OFF + e] - (pos - ws[POFF_OFF + e]);
    if (n > TOK) n = TOK;   // n >= 1 by construction

    int t = threadIdx.x;
    if (t < TOK) ptok[t] = ws[PERM_OFF + pos + ((t < n) ? t : 0)];

    // each wave owns a disjoint 32-channel slice: block reads each weight row once
    int cgrp = (t >> 6) * 8 + (t & 7);   // 0..31
    int tgrp = (t >> 3) & 7;             // 0..7
    int c0 = 4 * cgrp;
    int tok0 = 4 * tgrp;

    __syncthreads();

    float acc[4][4];            // [token][channel]
    {
        float bi[4], b2[4];
        LD4(bi, b_in    + (size_t)e * CH + c0);
        LD4(b2, b_init2 + (size_t)e * CH + c0);
        #pragma unroll
        for (int tt = 0; tt < 4; tt++)
            #pragma unroll
            for (int cc = 0; cc < 4; cc++)
                acc[tt][cc] = bi[cc] + b2[cc];
    }

    const float* WinE   = Win   + (size_t)e * CS * CH;
    const float* WinitE = Winit + (size_t)e * CS * CH;

    float4 wa0[4], wb0[4], wa1[4], wb1[4];

    // ---- h = relu(s) @ Win + relu(s_init) @ Winit + biases ----
    for (int kc = 0; kc < CS; kc += KC) {
        __syncthreads();
        for (int idx = t; idx < TOK * (KC / 4); idx += TPB) {
            int i = idx >> 5;          // KC/4 == 32
            int c4 = idx & 31;
            float4 v = make_float4(0.f, 0.f, 0.f, 0.f);
            float4 w = make_float4(0.f, 0.f, 0.f, 0.f);
            if (i < n) {
                v = *(const float4*)(s  + (size_t)ptok[i] * CS + kc + 4 * c4);
                w = *(const float4*)(si + (size_t)ptok[i] * CS + kc + 4 * c4);
            }
            v.x = fmaxf(v.x, 0.f); v.y = fmaxf(v.y, 0.f);
            v.z = fmaxf(v.z, 0.f); v.w = fmaxf(v.w, 0.f);
            w.x = fmaxf(w.x, 0.f); w.y = fmaxf(w.y, 0.f);
            w.z = fmaxf(w.z, 0.f); w.w = fmaxf(w.w, 0.f);
            *(float4*)&smem[0][i][4 * c4] = v;
            *(float4*)&smem[1][i][4 * c4] = w;
        }
        PRELOAD2(wa0, wb0, WinE, WinitE, kc);   // overlap with barrier drain
        __syncthreads();

        for (int k4 = 0; k4 < KC; k4 += 8) {
            PRELOAD2(wa1, wb1, WinE, WinitE, kc + k4 + 4);
            {
                float aA[4][4], aB[4][4];
                #pragma unroll
                for (int tt = 0; tt < 4; tt++) {
                    LD4(aA[tt], &smem[0][tok0 + tt][k4]);
                    LD4(aB[tt], &smem[1][tok0 + tt][k4]);
                }
                #pragma unroll
                for (int kk = 0; kk < 4; kk++)
                    #pragma unroll
                    for (int tt = 0; tt < 4; tt++)
                        #pragma unroll
                        for (int cc = 0; cc < 4; cc++)
                            acc[tt][cc] = fmaf(aA[tt][kk], WF(wa0, kk, cc),
                                          fmaf(aB[tt][kk], WF(wb0, kk, cc), acc[tt][cc]));
            }
            int kn = kc + k4 + 8;
            if (kn > CS - 4) kn = CS - 4;
            PRELOAD2(wa0, wb0, WinE, WinitE, kn);
            {
                float aA[4][4], aB[4][4];
                #pragma unroll
                for (int tt = 0; tt < 4; tt++) {
                    LD4(aA[tt], &smem[0][tok0 + tt][k4 + 4]);
                    LD4(aB[tt], &smem[1][tok0 + tt][k4 + 4]);
                }
                #pragma unroll
                for (int kk = 0; kk < 4; kk++)
                    #pragma unroll
                    for (int tt = 0; tt < 4; tt++)
                        #pragma unroll
                        for (int cc = 0; cc < 4; cc++)
                            acc[tt][cc] = fmaf(aA[tt][kk], WF(wa1, kk, cc),
                                          fmaf(aB[tt][kk], WF(wb1, kk, cc), acc[tt][cc]));
            }
        }
    }

    // ---- 2 residual blocks ----
    for (int b = 0; b < NBLK; b++) {
        const float* W1 = Wb1 + (size_t)(e * NBLK + b) * CH * CH;
        const float* W2 = Wb2 + (size_t)(e * NBLK + b) * CH * CH;

        __syncthreads();
        #pragma unroll
        for (int tt = 0; tt < 4; tt++) {
            float4 v = make_float4(fmaxf(acc[tt][0], 0.f), fmaxf(acc[tt][1], 0.f),
                                   fmaxf(acc[tt][2], 0.f), fmaxf(acc[tt][3], 0.f));
            *(float4*)&smem[0][tok0 + tt][c0] = v;
        }
        PRELOAD1(wa0, W1, 0);
        __syncthreads();

        float a2[4][4];
        {
            float bb[4];
            LD4(bb, bb1 + (size_t)(e * NBLK + b) * CH + c0);
            #pragma unroll
            for (int tt = 0; tt < 4; tt++)
                #pragma unroll
                for (int cc = 0; cc < 4; cc++) a2[tt][cc] = bb[cc];
        }
        for (int k4 = 0; k4 < CH; k4 += 8) {
            PRELOAD1(wa1, W1, k4 + 4);
            {
                float hv[4][4];
                #pragma unroll
                for (int tt = 0; tt < 4; tt++) LD4(hv[tt], &smem[0][tok0 + tt][k4]);
                #pragma unroll
                for (int kk = 0; kk < 4; kk++)
                    #pragma unroll
                    for (int tt = 0; tt < 4; tt++)
                        #pragma unroll
                        for (int cc = 0; cc < 4; cc++)
                            a2[tt][cc] = fmaf(hv[tt][kk], WF(wa0, kk, cc), a2[tt][cc]);
            }
            int kn = k4 + 8;
            if (kn > CH - 4) kn = CH - 4;
            PRELOAD1(wa0, W1, kn);
            {
                float hv[4][4];
                #pragma unroll
                for (int tt = 0; tt < 4; tt++) LD4(hv[tt], &smem[0][tok0 + tt][k4 + 4]);
                #pragma unroll
                for (int kk = 0; kk < 4; kk++)
                    #pragma unroll
                    for (int tt = 0; tt < 4; tt++)
                        #pragma unroll
                        for (int cc = 0; cc < 4; cc++)
                            a2[tt][cc] = fmaf(hv[tt][kk], WF(wa1, kk, cc), a2[tt][cc]);
            }
        }
        __syncthreads();
        #pragma unroll
        for (int tt = 0; tt < 4; tt++) {
            float4 v = make_float4(fmaxf(a2[tt][0], 0.f), fmaxf(a2[tt][1], 0.f),
                                   fmaxf(a2[tt][2], 0.f), fmaxf(a2[tt][3], 0.f));
            *(float4*)&smem[1][tok0 + tt][c0] = v;
        }
        PRELOAD1(wa0, W2, 0);
        __syncthreads();

        {
            float bb[4];
            LD4(bb, bb2 + (size_t)(e * NBLK + b) * CH + c0);
            #pragma unroll
            for (int tt = 0; tt < 4; tt++)
                #pragma unroll
                for (int cc = 0; cc < 4; cc++) a2[tt][cc] = bb[cc];
        }
        for (int k4 = 0; k4 < CH; k4 += 8) {
            PRELOAD1(wa1, W2, k4 + 4);
            {
                float av[4][4];
                #pragma unroll
                for (int tt = 0; tt < 4; tt++) LD4(av[tt], &smem[1][tok0 + tt][k4]);
                #pragma unroll
                for (int kk = 0; kk < 4; kk++)
                    #pragma unroll
                    for (int tt = 0; tt < 4; tt++)
                        #pragma unroll
                        for (int cc = 0; cc < 4; cc++)
                            a2[tt][cc] = fmaf(av[tt][kk], WF(wa0, kk, cc), a2[tt][cc]);
            }
            int kn = k4 + 8;
            if (kn > CH - 4) kn = CH - 4;
            PRELOAD1(wa0, W2, kn);
            {
                float av[4][4];
                #pragma unroll
                for (int tt = 0; tt < 4; tt++) LD4(av[tt], &smem[1][tok0 + tt][k4 + 4]);
                #pragma unroll
                for (int kk = 0; kk < 4; kk++)
                    #pragma unroll
                    for (int tt = 0; tt < 4; tt++)
                        #pragma unroll
                        for (int cc = 0; cc < 4; cc++)
                            a2[tt][cc] = fmaf(av[tt][kk], WF(wa1, kk, cc), a2[tt][cc]);
            }
        }
        #pragma unroll
        for (int tt = 0; tt < 4; tt++)
            #pragma unroll
            for (int cc = 0; cc < 4; cc++) acc[tt][cc] += a2[tt][cc];
    }

    // ---- final relu(h) -> LDS ----
    __syncthreads();
    #pragma unroll
    for (int tt = 0; tt < 4; tt++) {
        float4 v = make_float4(fmaxf(acc[tt][0], 0.f), fmaxf(acc[tt][1], 0.f),
                               fmaxf(acc[tt][2], 0.f), fmaxf(acc[tt][3], 0.f));
        *(float4*)&smem[0][tok0 + tt][c0] = v;
    }
    __syncthreads();

    // ---- out = relu(h) @ Wout + b_out (128 -> 14) ----
    const float* WoutE = Wout + (size_t)e * CH * (NANG * 2);
    const float* boutE = b_out + (size_t)e * (NANG * 2);
    for (int idx = t; idx < n * (NANG * 2); idx += TPB) {
        int i = idx / (NANG * 2);
        int o = idx % (NANG * 2);
        float v = boutE[o];
        #pragma unroll 4
        for (int k = 0; k < CH; k++)
            v = fmaf(smem[0][i][k], WoutE[(size_t)k * (NANG * 2) + o], v);
        smem[1][i][o] = v;
    }
    __syncthreads();

    // ---- pair-normalize and store ----
    for (int idx = t; idx < n * NANG; idx += TPB) {
        int i = idx / NANG;
        int a = idx % NANG;
        float x = smem[1][i][2 * a];
        float y = smem[1][i][2 * a + 1];
        float nr = fmaxf(sqrtf(x * x + y * y), 1e-12f);
        size_t base = (size_t)ptok[i] * (NANG * 2) + 2 * a;
        out[base]     = x / nr;
        out[base + 1] = y / nr;
    }
}

extern "C" void kernel_launch(void* const* d_in, const int* in_sizes, int n_in,
                              void* d_out, int out_size, void* d_ws, size_t ws_size,
                              hipStream_t stream) {
    const float* s       = (const float*)d_in[0];
    const float* s_init  = (const float*)d_in[1];
    const int*   aatype  = (const int*)d_in[2];
    const float* Win     = (const float*)d_in[3];
    const float* b_in    = (const float*)d_in[4];
    const float* Winit   = (const float*)d_in[5];
    const float* b_init2 = (const float*)d_in[6];
    const float* Wb1     = (const float*)d_in[7];
    const float* bb1     = (const float*)d_in[8];
    const float* Wb2     = (const float*)d_in[9];
    const float* bb2     = (const float*)d_in[10];
    const float* Wout    = (const float*)d_in[11];
    const float* b_out   = (const float*)d_in[12];
    int*   ws  = (int*)d_ws;
    float* out = (float*)d_out;

    hipMemsetAsync(ws, 0, 512, stream);   // zero counts/cursors/poff region
    hipLaunchKernelGGL(count_k, dim3(N_TOK / 256), dim3(256), 0, stream, aatype, ws);
    hipLaunchKernelGGL(offs_k, dim3(1), dim3(64), 0, stream, ws);
    hipLaunchKernelGGL(scatter_k, dim3(N_TOK / 256), dim3(256), 0, stream, aatype, ws);
    hipLaunchKernelGGL(angle_main, dim3(MAX_TILES), dim3(TPB), 0, stream,
                       s, s_init, Win, b_in, Winit, b_init2,
                       Wb1, bb1, Wb2, bb2, Wout, b_out, ws, out);
}